// Round 3
// baseline (7543.034 us; speedup 1.0000x reference)
//
#include <hip/hip_runtime.h>
#include <stdint.h>
#include <stddef.h>

typedef __attribute__((ext_vector_type(8))) short short8;
typedef __attribute__((ext_vector_type(4))) float floatx4;

#define Bn 8
#define Cn 32
#define Hn 512
#define Wn 512
#define NCH 32   // chunks per batch
#define RR 16    // rows per chunk
#define NWG (Bn*NCH)   // 256
#define PST 40   // P row stride (bf16 elems); 80B = multiple of 16B for b128 reads

__device__ __forceinline__ unsigned short f2bf(float f) {
  union { float f; unsigned int i; } v; v.f = f;
  unsigned int x = v.i;
  unsigned int r = x + 0x7fffu + ((x >> 16) & 1u);  // RNE
  return (unsigned short)(r >> 16);
}
__device__ __forceinline__ float sigmoidf_(float x) {
  return 1.0f / (1.0f + __expf(-x));
}
__device__ __forceinline__ float tanhf_(float x) {
  // safe for all finite x: exp->inf gives 1, exp->0 gives -1
  return 1.0f - 2.0f / (__expf(2.0f * x) + 1.0f);
}

// One wave (64 threads) per workgroup; one workgroup per (batch, H-chunk).
// b = blockIdx%8, j = blockIdx/8 -> chunks of one batch land on one XCD.
// 256 single-wave blocks on 256 CUs are trivially co-resident, so the
// neighbor spin-wait cannot starve. ALL global I/O is float32 (reference
// dtype); bf16 exists only as MFMA operands + LDS state + boundary words.
__global__ __launch_bounds__(64, 1) void sdn_scan(
    const float* __restrict__ states,  // (B,C,H,W) f32
    const float* __restrict__ wih,     // (96,96) f32
    const float* __restrict__ bih,     // (96)
    const float* __restrict__ whh,     // (96,32)
    const float* __restrict__ bhh,     // (96)
    float* __restrict__ out,           // (B,C,H,W) f32
    unsigned int* __restrict__ bnd,    // [NWG][2][32] uint (2 bf16 packed)
    int* __restrict__ flags)           // [NWG][2] column tags
{
  const int lane = threadIdx.x;
  const int wg = blockIdx.x;
  const int b = wg & 7;      // batch
  const int j = wg >> 3;     // chunk within batch
  const int h0 = j * RR;
  const int lm = lane & 15;  // m (row) for A, n (out col) for B/C
  const int lg = lane >> 4;  // k-group / row-group

  __shared__ __align__(16) unsigned short P[18 * PST];  // prev column (bf16), rows h0-1..h0+16

  // ---- persistent weight fragments (B-operand layout: B[k][n], n=lane&15, k=lg*8+t) ----
  short8 wf[6][3];  // W_ih: 6 o-tiles x 3 k-slices
  short8 hf[6];     // W_hh: 6 o-tiles x 1 k-slice
  float bi[6], bh[6];
  for (int ot = 0; ot < 6; ++ot) {
    for (int ks = 0; ks < 3; ++ks) {
      short8 v;
#pragma unroll
      for (int t = 0; t < 8; ++t)
        v[t] = (short)f2bf(wih[(size_t)(16 * ot + lm) * 96 + 32 * ks + lg * 8 + t]);
      wf[ot][ks] = v;
    }
    short8 v;
#pragma unroll
    for (int t = 0; t < 8; ++t)
      v[t] = (short)f2bf(whh[(size_t)(16 * ot + lm) * 32 + lg * 8 + t]);
    hf[ot] = v;
    bi[ot] = bih[16 * ot + lm];   // biases stay exact f32 (enter via MFMA C-init)
    bh[ot] = bhh[16 * ot + lm];
  }

  // ---- load column 0 (with halo rows, zero-padded at batch edges) into P ----
  for (int t = lane; t < 18 * 32; t += 64) {
    int r = t >> 5, c = t & 31;
    int h = h0 + r - 1;
    unsigned short v = 0;
    if (h >= 0 && h < Hn)
      v = f2bf(states[(((size_t)b * Cn + c) * Hn + h) * Wn + 0]);
    P[r * PST + c] = v;
  }
  // ---- column 0 of output = input column 0 (exact f32 copy) ----
  for (int t = lane; t < RR * 32; t += 64) {
    int r = t >> 5, c = t & 31;
    size_t idx = (((size_t)b * Cn + c) * Hn + (h0 + r)) * Wn + 0;
    out[idx] = states[idx];
  }

  // ---- preload cur column 1 ----
  // A-layout for the h_vals MFMA: A[m=lm][k=lg*8+t] = cur[row=lm][c=k]
  short8 curA;
#pragma unroll
  for (int t = 0; t < 8; ++t) {
    int c = lg * 8 + t;
    curA[t] = (short)f2bf(states[(((size_t)b * Cn + c) * Hn + (h0 + lm)) * Wn + 1]);
  }
  // C-layout for the final blend: element (row=lg*4+i, c=16*t+lm), exact f32
  float curC[2][4];
#pragma unroll
  for (int t = 0; t < 2; ++t)
#pragma unroll
    for (int i = 0; i < 4; ++i)
      curC[t][i] = states[(((size_t)b * Cn + (16 * t + lm)) * Hn + (h0 + lg * 4 + i)) * Wn + 1];

  for (int w = 1; w < Wn; ++w) {
    // ---- A fragments of prev column from LDS (3 H-shifted slices) ----
    // x[m][32*ks + k'] = prevcol[m-1+ks][k'] = P[(m+ks)][k']
    short8 af[3];
#pragma unroll
    for (int ks = 0; ks < 3; ++ks)
      af[ks] = *(const short8*)&P[(lm + ks) * PST + lg * 8];

    // ---- MFMA: I = b_ih + X*W_ih^T ; Hh = b_hh + cur*W_hh^T ----
    floatx4 I[6], Hh[6];
#pragma unroll
    for (int ot = 0; ot < 6; ++ot) {
      I[ot] = (floatx4){bi[ot], bi[ot], bi[ot], bi[ot]};
      Hh[ot] = (floatx4){bh[ot], bh[ot], bh[ot], bh[ot]};
#pragma unroll
      for (int ks = 0; ks < 3; ++ks)
        I[ot] = __builtin_amdgcn_mfma_f32_16x16x32_bf16(af[ks], wf[ot][ks], I[ot], 0, 0, 0);
      Hh[ot] = __builtin_amdgcn_mfma_f32_16x16x32_bf16(curA, hf[ot], Hh[ot], 0, 0, 0);
    }

    // ---- gates + write output (f32) + stage new column into P (bf16, rows 1..16) ----
#pragma unroll
    for (int t = 0; t < 2; ++t) {
#pragma unroll
      for (int i = 0; i < 4; ++i) {
        float rv = sigmoidf_(I[t][i] + Hh[t][i]);
        float zv = sigmoidf_(I[2 + t][i] + Hh[2 + t][i]);
        float nv = tanhf_(I[4 + t][i] + rv * Hh[4 + t][i]);
        float ov = curC[t][i] + zv * (nv - curC[t][i]);
        int c = 16 * t + lm;
        int r = lg * 4 + i;
        out[(((size_t)b * Cn + c) * Hn + (h0 + r)) * Wn + w] = ov;
        P[(1 + r) * PST + c] = f2bf(ov);  // wave-private LDS; DS ops in-order per wave
      }
    }

    // ---- publish boundary rows (local rows 0 and 15 of the new column) ----
    if (lane < 32) {
      int rr = lane >> 4;            // 0 -> row0 (P row 1), 1 -> row15 (P row 16)
      int cc = (lane & 15) * 2;
      unsigned int lo = P[(1 + 15 * rr) * PST + cc];
      unsigned int hi = P[(1 + 15 * rr) * PST + cc + 1];
      __hip_atomic_store(&bnd[wg * 64 + (w & 1) * 32 + lane], lo | (hi << 16),
                         __ATOMIC_RELAXED, __HIP_MEMORY_SCOPE_AGENT);
    }
    if (lane == 0)
      __hip_atomic_store(&flags[wg * 2 + (w & 1)], w,
                         __ATOMIC_RELEASE, __HIP_MEMORY_SCOPE_AGENT);

    if (w + 1 < Wn) {
      // ---- prefetch cur column w+1 NOW; latency hides behind the spin-wait ----
      short8 nA;
      float nC[2][4];
#pragma unroll
      for (int t = 0; t < 8; ++t) {
        int c = lg * 8 + t;
        nA[t] = (short)f2bf(states[(((size_t)b * Cn + c) * Hn + (h0 + lm)) * Wn + (w + 1)]);
      }
#pragma unroll
      for (int t = 0; t < 2; ++t)
#pragma unroll
        for (int i = 0; i < 4; ++i)
          nC[t][i] = states[(((size_t)b * Cn + (16 * t + lm)) * Hn + (h0 + lg * 4 + i)) * Wn + (w + 1)];

      // ---- fetch neighbor halo rows of column w (needed for column w+1) ----
      if (j > 0) {  // up neighbor's bottom row -> P row 0
        const int nb = wg - 8;
        int spins = 0;
        while (__hip_atomic_load(&flags[nb * 2 + (w & 1)], __ATOMIC_ACQUIRE,
                                 __HIP_MEMORY_SCOPE_AGENT) != w) {
          __builtin_amdgcn_s_sleep(2);
          if (++spins > (1 << 20)) break;  // fail loud (wrong result), not hung
        }
        if (lane < 16) {
          unsigned int v = __hip_atomic_load(&bnd[nb * 64 + (w & 1) * 32 + 16 + lane],
                                             __ATOMIC_RELAXED, __HIP_MEMORY_SCOPE_AGENT);
          P[0 * PST + 2 * lane] = (unsigned short)(v & 0xffffu);
          P[0 * PST + 2 * lane + 1] = (unsigned short)(v >> 16);
        }
      }
      if (j < NCH - 1) {  // down neighbor's top row -> P row 17
        const int nb = wg + 8;
        int spins = 0;
        while (__hip_atomic_load(&flags[nb * 2 + (w & 1)], __ATOMIC_ACQUIRE,
                                 __HIP_MEMORY_SCOPE_AGENT) != w) {
          __builtin_amdgcn_s_sleep(2);
          if (++spins > (1 << 20)) break;
        }
        if (lane < 16) {
          unsigned int v = __hip_atomic_load(&bnd[nb * 64 + (w & 1) * 32 + lane],
                                             __ATOMIC_RELAXED, __HIP_MEMORY_SCOPE_AGENT);
          P[17 * PST + 2 * lane] = (unsigned short)(v & 0xffffu);
          P[17 * PST + 2 * lane + 1] = (unsigned short)(v >> 16);
        }
      }

      curA = nA;
#pragma unroll
      for (int t = 0; t < 2; ++t)
#pragma unroll
        for (int i = 0; i < 4; ++i)
          curC[t][i] = nC[t][i];
    }
  }
}

extern "C" void kernel_launch(void* const* d_in, const int* in_sizes, int n_in,
                              void* d_out, int out_size, void* d_ws, size_t ws_size,
                              hipStream_t stream) {
  const float* states = (const float*)d_in[0];
  const float* wih = (const float*)d_in[1];
  const float* bih = (const float*)d_in[2];
  const float* whh = (const float*)d_in[3];
  const float* bhh = (const float*)d_in[4];
  float* outp = (float*)d_out;

  unsigned int* bnd = (unsigned int*)d_ws;                          // NWG*2*32 uints = 64 KB
  int* flags = (int*)((char*)d_ws + (size_t)NWG * 64 * sizeof(unsigned int));  // NWG*2 ints

  // zero the column-tag flags each call (ws is re-poisoned by the harness)
  hipMemsetAsync(flags, 0, (size_t)NWG * 2 * sizeof(int), stream);

  sdn_scan<<<dim3(NWG), dim3(64), 0, stream>>>(states, wih, bih, whh, bhh, outp, bnd, flags);
}